// Round 13
// baseline (24.057 us; speedup 1.0000x reference)
//
#include <hip/hip_runtime.h>
#include <stdint.h>

// LTI all-pass: cascade of 8 second-order all-pass sections (DF2T):
//   y = B2*x + s1 ; s1' = B1*(x-y) + s2 ; s2' = x - B2*y
// Cascade = z^-16 A(1/z)/A(z) = B(z)/A(z) with b = a[::-1] (the reference).
//
// Overlap-and-discard: mag <= sigmoid(1.3608)*0.99 = 0.7881 (hard bound).
// WARM=32: absmax 0.0156 measured (R8/R10/R12), 7x under 0.112 threshold.
//
// Round-13: double-buffered HALF windows at R10's occupancy. R11 proved
// 2-window pipelining loses if it halves occupancy (34KB LDS); R12 proved
// compute isn't the binder. Here: WAVE_WIN=2048 -> 9KB per window buffer,
// 2 buffers = 18KB/block -> still 8 blocks/CU = 2 waves/SIMD, AND the
// counted-vmcnt pipeline: DMA-A(9)+DMA-B(9) up front; vmcnt(9) = A ready
// (B stays in flight); compute+store A under B's loads; vmcnt(8) retires
// exactly B's DMA (A's 8 stores excluded, drain under B's compute).
// All R10 machinery kept: 16B DMA granularity, chunk-XOR swizzle
// csw(c) = c ^ ((c>>4)&15) (involutive; linear LDS dest, pre-swizzled
// global source), register-staged compute, coalesced dwordx4 copy-out.

#define NROOTS 8
#define BATCH  32
#define TLEN   262144
#define CHUNK  32                      // output floats per lane per window
#define WARM   32                      // discarded warm-up floats per lane
#define WAVE_WIN 2048                  // output floats per window
#define PIECE_CH ((WAVE_WIN + WARM) / 4)   // 520 valid 16B chunks
#define NQ     9                       // DMA16 instructions per window
#define SEGF   (NQ * 256)              // 2304 LDS floats per buffer (9 KB)
#define BPR    (TLEN / (2 * WAVE_WIN)) // 64 blocks per row

__device__ __forceinline__ int csw(int c) { return c ^ ((c >> 4) & 15); }

__global__ __launch_bounds__(64) void allpass_kernel(
    const float* __restrict__ x,
    const float* __restrict__ mag_logits,
    const float* __restrict__ cos_logits,
    float* __restrict__ y)
{
    __shared__ float segA[SEGF], segB[SEGF];   // 18 KB

    const int lane = threadIdx.x;      // 0..63
    const int brow = blockIdx.x >> 6;  // / BPR
    const int bcol = blockIdx.x & (BPR - 1);
    const bool firstA = (bcol == 0);   // window A at row head (B never is)
    const long g0A = (long)brow * TLEN + (long)(2 * bcol) * WAVE_WIN - WARM;
    const long g0B = g0A + WAVE_WIN;

    // coefficient loads first: oldest vmcnt entries, retired by the
    // compiler's own wait before expf/tanh use (vmcnt(18): DMAs unaffected)
    const float mlv = mag_logits[lane & 7];
    const float clv = cos_logits[lane & 7];

    // ---- issue DMA for BOTH windows (9 + 9 insts, issue order = A then B).
    //      Slot chunk s holds global chunk csw(s) (involution => global
    //      chunk c at slot csw(c)); LDS dest linear (HW: base + lane*16B).
#pragma unroll
    for (int q = 0; q < NQ; ++q) {
        int sc = csw(64 * q + lane);
        if (q == 0 && firstA) sc = max(sc, WARM / 4);     // row head guard
        if (q == NQ - 1)      sc = min(sc, PIECE_CH - 1); // tail clamp
        __builtin_amdgcn_global_load_lds(
            (const __attribute__((address_space(1))) uint32_t*)(x + g0A + 4 * sc),
            (__attribute__((address_space(3))) uint32_t*)(segA + 256 * q),
            16, 0, 0);
    }
#pragma unroll
    for (int q = 0; q < NQ; ++q) {
        int sc = csw(64 * q + lane);
        if (q == NQ - 1) sc = min(sc, PIECE_CH - 1);      // tail clamp
        __builtin_amdgcn_global_load_lds(
            (const __attribute__((address_space(1))) uint32_t*)(x + g0B + 4 * sc),
            (__attribute__((address_space(3))) uint32_t*)(segB + 256 * q),
            16, 0, 0);
    }

    // ---- coefficients while both DMA streams fly ----
    float mm  = 0.99f / (1.0f + expf(-mlv));
    float cc  = tanhf(clv);
    float b1v = -2.0f * mm * cc;
    float b2v = mm * mm;
    float B1[NROOTS], B2[NROOTS], s1[NROOTS], s2[NROOTS];
#pragma unroll
    for (int s = 0; s < NROOTS; ++s) {
        B1[s] = __shfl(b1v, s);
        B2[s] = __shfl(b2v, s);
    }

    auto step = [&](float v) -> float {
#pragma unroll
        for (int s = 0; s < NROOTS; ++s) {
            float o = fmaf(B2[s], v, s1[s]);
            s1[s] = fmaf(B1[s], v - o, s2[s]);
            s2[s] = fmaf(-B2[s], o, v);          // neg folds into VOP3 modifier
            v = o;
        }
        return v;
    };

    // lane l: window floats [32l, 32l+64) = chunks [8l, 8l+16);
    // outputs = chunks [8l+8, 8l+16).
    const int c0 = 8 * lane;
    float r[WARM + CHUNK];             // 64 floats, all indices static

    // ================= window A =================
    // Outstanding: 9 (A) + 9 (B); coeffs already retired. Wait A only.
    asm volatile("s_waitcnt vmcnt(9)" ::: "memory");

    // exact zero history at row head: chunks 0..7 have csw(c)=c -> linear
    if (firstA && lane < WARM) segA[lane] = 0.0f;

#pragma unroll
    for (int s = 0; s < NROOTS; ++s) { s1[s] = 0.0f; s2[s] = 0.0f; }
#pragma unroll
    for (int t = 0; t < 16; ++t) {     // 16 x ds_read_b128
        const float4 v = *reinterpret_cast<const float4*>(segA + 4 * csw(c0 + t));
        r[4 * t] = v.x; r[4 * t + 1] = v.y; r[4 * t + 2] = v.z; r[4 * t + 3] = v.w;
    }
#pragma unroll
    for (int i = 0; i < WARM; ++i) step(r[i]);
#pragma unroll
    for (int i = 0; i < CHUNK; ++i) r[WARM + i] = step(r[WARM + i]);
#pragma unroll
    for (int t = 8; t < 16; ++t) {     // 8 x ds_write_b128 (after ALL reads)
        float4 v;
        v.x = r[4 * t]; v.y = r[4 * t + 1]; v.z = r[4 * t + 2]; v.w = r[4 * t + 3];
        *reinterpret_cast<float4*>(segA + 4 * csw(c0 + t)) = v;
    }
    {   // copy-out A: 8 x (ds_read_b128 + coalesced dwordx4 store)
        float* gdst = y + g0A + WARM;
#pragma unroll
        for (int k = 0; k < 8; ++k) {
            const int oc = 64 * k + lane;
            const float4 v = *reinterpret_cast<const float4*>(segA + 4 * csw(oc + WARM / 4));
            *reinterpret_cast<float4*>(gdst + 4 * oc) = v;
        }
    }

    // ================= window B =================
    // Outstanding: B's 9 DMA (older) + A's 8 stores (newer) = 17.
    // vmcnt(8) retires >=9 oldest = all of B's DMA; A's stores drain
    // in the background under B's compute.
    asm volatile("s_waitcnt vmcnt(8)" ::: "memory");

#pragma unroll
    for (int s = 0; s < NROOTS; ++s) { s1[s] = 0.0f; s2[s] = 0.0f; }
#pragma unroll
    for (int t = 0; t < 16; ++t) {
        const float4 v = *reinterpret_cast<const float4*>(segB + 4 * csw(c0 + t));
        r[4 * t] = v.x; r[4 * t + 1] = v.y; r[4 * t + 2] = v.z; r[4 * t + 3] = v.w;
    }
#pragma unroll
    for (int i = 0; i < WARM; ++i) step(r[i]);
#pragma unroll
    for (int i = 0; i < CHUNK; ++i) r[WARM + i] = step(r[WARM + i]);
#pragma unroll
    for (int t = 8; t < 16; ++t) {
        float4 v;
        v.x = r[4 * t]; v.y = r[4 * t + 1]; v.z = r[4 * t + 2]; v.w = r[4 * t + 3];
        *reinterpret_cast<float4*>(segB + 4 * csw(c0 + t)) = v;
    }
    {
        float* gdst = y + g0B + WARM;
#pragma unroll
        for (int k = 0; k < 8; ++k) {
            const int oc = 64 * k + lane;
            const float4 v = *reinterpret_cast<const float4*>(segB + 4 * csw(oc + WARM / 4));
            *reinterpret_cast<float4*>(gdst + 4 * oc) = v;
        }
    }
}

extern "C" void kernel_launch(void* const* d_in, const int* in_sizes, int n_in,
                              void* d_out, int out_size, void* d_ws, size_t ws_size,
                              hipStream_t stream) {
    const float* ex = (const float*)d_in[0];
    const float* ml = (const float*)d_in[1];
    const float* cl = (const float*)d_in[2];
    float* yo = (float*)d_out;

    allpass_kernel<<<BATCH * BPR, 64, 0, stream>>>(ex, ml, cl, yo);
}